// Round 11
// baseline (359.151 us; speedup 1.0000x reference)
//
#include <hip/hip_runtime.h>
#include <stdint.h>

// ---------------------------------------------------------------------------
// GCN: agg1 = A_hat x (8-deep gather + BOTH dropout-mask bitmaps)
//      h    = relu+drop(agg1 W1 + b1)   (MFMA GEMM, mask1 bit-test)
//      hw2  = h W2                      (MFMA GEMM, plain)
//      out  = relu+drop(A_hat hw2 + b2) (8-deep gather + mask2 bit-test)
// GEMMs: swapped-operand MFMA (direct 8B C stores), single-buffer 32KB LDS,
// 1-D grid with bijective XCD swizzle (y-fastest) for A-tile/W L2 reuse.
// All threefry lives in the memory-bound gather1 (proven free there).
// ---------------------------------------------------------------------------

#define N_NODES 50000
#define N_EDGES 800000
#define M_PAD   50048   // 391 * 128
#define IN_C 256
#define HID_C 512
#define OUT_C 256

typedef __attribute__((ext_vector_type(8))) short bf16x8;
typedef __attribute__((ext_vector_type(4))) float f32x4;

struct U2 { unsigned a, b; };

__host__ __device__ constexpr unsigned rotl32(unsigned x, int d) {
  return (x << d) | (x >> (32 - d));
}

#define TF_ROUND(r) { x0 += x1; x1 = rotl32(x1, (r)); x1 ^= x0; }

__host__ __device__ constexpr U2 threefry2x32(unsigned k0, unsigned k1,
                                              unsigned x0, unsigned x1) {
  unsigned ks2 = k0 ^ k1 ^ 0x1BD11BDAu;
  x0 += k0; x1 += k1;
  TF_ROUND(13) TF_ROUND(15) TF_ROUND(26) TF_ROUND(6)  x0 += k1;  x1 += ks2 + 1u;
  TF_ROUND(17) TF_ROUND(29) TF_ROUND(16) TF_ROUND(24) x0 += ks2; x1 += k0 + 2u;
  TF_ROUND(13) TF_ROUND(15) TF_ROUND(26) TF_ROUND(6)  x0 += k0;  x1 += k1 + 3u;
  TF_ROUND(17) TF_ROUND(29) TF_ROUND(16) TF_ROUND(24) x0 += k1;  x1 += ks2 + 4u;
  TF_ROUND(13) TF_ROUND(15) TF_ROUND(26) TF_ROUND(6)  x0 += ks2; x1 += k0 + 5u;
  return U2{x0, x1};
}

__device__ __forceinline__ ushort f2b(float f) {  // RTNE
  unsigned u = __builtin_bit_cast(unsigned, f);
  unsigned r = (u + 0x7fffu + ((u >> 16) & 1u)) >> 16;
  return (ushort)r;
}
__device__ __forceinline__ float b2f(ushort h) {
  unsigned u = (unsigned)h << 16;
  return __builtin_bit_cast(float, u);
}

__device__ __forceinline__ void gload16(const void* g, void* l) {
  __builtin_amdgcn_global_load_lds(
      (const __attribute__((address_space(1))) void*)g,
      (__attribute__((address_space(3))) void*)l, 16, 0, 0);
}

// ---------------------------------------------------------------------------
// degree / scan(+dinv) / CSR build (CSR entry = {src, dinv[src]})
// ---------------------------------------------------------------------------
__global__ void deg_kernel(const int* __restrict__ col, int* __restrict__ cnt, int E) {
  int e = blockIdx.x * 256 + threadIdx.x;
  if (e < E) atomicAdd(&cnt[col[e]], 1);
}

__global__ __launch_bounds__(1024) void scan_local(const int* __restrict__ cnt,
                                                   int* __restrict__ indptr,
                                                   int* __restrict__ chunkSums,
                                                   float* __restrict__ dinv, int n) {
  __shared__ int s[1024];
  int gid = blockIdx.x * 1024 + threadIdx.x;
  int v = (gid < n) ? cnt[gid] : 0;
  if (gid < n) dinv[gid] = rsqrtf((float)v + 1.0f);
  s[threadIdx.x] = v;
  __syncthreads();
#pragma unroll
  for (int off = 1; off < 1024; off <<= 1) {
    int t = (threadIdx.x >= off) ? s[threadIdx.x - off] : 0;
    __syncthreads();
    s[threadIdx.x] += t;
    __syncthreads();
  }
  if (gid < n) indptr[gid] = s[threadIdx.x] - v;
  if (threadIdx.x == 1023) chunkSums[blockIdx.x] = s[1023];
}

__global__ void scan_chunks(int* __restrict__ chunkSums, int nChunks) {
  if (threadIdx.x == 0 && blockIdx.x == 0) {
    int acc = 0;
    for (int i = 0; i < nChunks; ++i) { int t = chunkSums[i]; chunkSums[i] = acc; acc += t; }
  }
}

__global__ void add_offsets(int* __restrict__ indptr, const int* __restrict__ chunkSums,
                            int n, int total) {
  int gid = blockIdx.x * 256 + threadIdx.x;
  if (gid < n) indptr[gid] += chunkSums[gid >> 10];
  if (gid == 0) indptr[n] = total;
}

__global__ void build_csr(const int* __restrict__ row, const int* __restrict__ col,
                          const int* __restrict__ indptr, int* __restrict__ cursor,
                          const float* __restrict__ dinv,
                          int2* __restrict__ srcW, int E) {
  int e = blockIdx.x * 256 + threadIdx.x;
  if (e < E) {
    int r = row[e];
    int c = col[e];
    int p = indptr[c] + atomicAdd(&cursor[c], 1);
    srcW[p] = make_int2(r, __builtin_bit_cast(int, dinv[r]));
  }
}

// ---------------------------------------------------------------------------
// converts
// ---------------------------------------------------------------------------
__global__ void cvt_f32_bf16(const float* __restrict__ in, ushort* __restrict__ out, int n4) {
  int i = blockIdx.x * 256 + threadIdx.x;
  if (i < n4) {
    float4 v = *(const float4*)(in + (size_t)i * 4);
    ushort4 o = make_ushort4(f2b(v.x), f2b(v.y), f2b(v.z), f2b(v.w));
    *(ushort4*)(out + (size_t)i * 4) = o;
  }
}

// W1T[n][k]=bf16(W1[k][n]) (256x512) and W2T[n][k]=bf16(W2[k][n]) (512x256)
__global__ void wT_both(const float* __restrict__ W1, const float* __restrict__ W2,
                        ushort* __restrict__ W1T, ushort* __restrict__ W2T) {
  int i = blockIdx.x * 256 + threadIdx.x;
  if (i < IN_C * HID_C) {
    int k = i & (IN_C - 1);
    int n = i >> 8;
    W1T[i] = f2b(W1[(size_t)k * HID_C + n]);
  } else {
    int j = i - IN_C * HID_C;
    int k = j & (HID_C - 1);
    int n = j >> 9;
    W2T[j] = f2b(W2[(size_t)k * OUT_C + n]);
  }
}

// ---------------------------------------------------------------------------
// gather over CSR pairs: one wave per node, 64 lanes x 8B, 8-deep unrolled.
// EPI=false: bf16 out + mask1 bitmap (all lanes, 8 bits) + mask2 bitmap
//            (lanes<32, 8 bits) — all threefry hides under the memory wall.
// EPI=true:  bias+relu+mask2-bit dropout, fp32 out.
// ---------------------------------------------------------------------------
#define ROW_ACC(vv, ww)                                                        \
  { a0 += b2f((vv).x) * (ww); a1 += b2f((vv).y) * (ww);                        \
    a2 += b2f((vv).z) * (ww); a3 += b2f((vv).w) * (ww); }

template <bool EPI>
__global__ __launch_bounds__(256) void gather8(const ushort* __restrict__ X,
                                               const int* __restrict__ indptr,
                                               const int2* __restrict__ srcW,
                                               const float* __restrict__ dinv,
                                               const float* __restrict__ bias,
                                               void* __restrict__ outp,
                                               unsigned char* __restrict__ mask1Gen,
                                               unsigned char* __restrict__ mask2Gen,
                                               const unsigned char* __restrict__ maskUse,
                                               unsigned k10, unsigned k11,
                                               unsigned k20, unsigned k21, int N) {
  int wid = (blockIdx.x * 256 + threadIdx.x) >> 6;
  int lane = threadIdx.x & 63;
  if (wid >= N) return;
  int beg = __builtin_amdgcn_readfirstlane(indptr[wid]);
  int end = __builtin_amdgcn_readfirstlane(indptr[wid + 1]);
  float dc = dinv[wid];
  const int f0 = lane * 4;
  ushort4 sv = *(const ushort4*)(X + (size_t)wid * 256 + f0);
  float a0 = b2f(sv.x) * dc, a1 = b2f(sv.y) * dc,
        a2 = b2f(sv.z) * dc, a3 = b2f(sv.w) * dc;

  int e = beg;
  for (; e + 8 <= end; e += 8) {
    int2 p0 = srcW[e + 0], p1 = srcW[e + 1], p2 = srcW[e + 2], p3 = srcW[e + 3];
    int2 p4 = srcW[e + 4], p5 = srcW[e + 5], p6 = srcW[e + 6], p7 = srcW[e + 7];
    ushort4 v0 = *(const ushort4*)(X + (size_t)p0.x * 256 + f0);
    ushort4 v1 = *(const ushort4*)(X + (size_t)p1.x * 256 + f0);
    ushort4 v2 = *(const ushort4*)(X + (size_t)p2.x * 256 + f0);
    ushort4 v3 = *(const ushort4*)(X + (size_t)p3.x * 256 + f0);
    ushort4 v4 = *(const ushort4*)(X + (size_t)p4.x * 256 + f0);
    ushort4 v5 = *(const ushort4*)(X + (size_t)p5.x * 256 + f0);
    ushort4 v6 = *(const ushort4*)(X + (size_t)p6.x * 256 + f0);
    ushort4 v7 = *(const ushort4*)(X + (size_t)p7.x * 256 + f0);
    ROW_ACC(v0, __builtin_bit_cast(float, p0.y));
    ROW_ACC(v1, __builtin_bit_cast(float, p1.y));
    ROW_ACC(v2, __builtin_bit_cast(float, p2.y));
    ROW_ACC(v3, __builtin_bit_cast(float, p3.y));
    ROW_ACC(v4, __builtin_bit_cast(float, p4.y));
    ROW_ACC(v5, __builtin_bit_cast(float, p5.y));
    ROW_ACC(v6, __builtin_bit_cast(float, p6.y));
    ROW_ACC(v7, __builtin_bit_cast(float, p7.y));
  }
  for (; e + 2 <= end; e += 2) {
    int2 p0 = srcW[e + 0], p1 = srcW[e + 1];
    ushort4 v0 = *(const ushort4*)(X + (size_t)p0.x * 256 + f0);
    ushort4 v1 = *(const ushort4*)(X + (size_t)p1.x * 256 + f0);
    ROW_ACC(v0, __builtin_bit_cast(float, p0.y));
    ROW_ACC(v1, __builtin_bit_cast(float, p1.y));
  }
  if (e < end) {
    int2 p0 = srcW[e];
    ushort4 v0 = *(const ushort4*)(X + (size_t)p0.x * 256 + f0);
    ROW_ACC(v0, __builtin_bit_cast(float, p0.y));
  }
  a0 *= dc; a1 *= dc; a2 *= dc; a3 *= dc;

  if (EPI) {
    float4 bv = *(const float4*)(bias + f0);
    unsigned mk = maskUse[(size_t)wid * 32 + (lane >> 1)];
    int sh = (lane & 1) * 4;
    float v0 = fmaxf(a0 + bv.x, 0.f);
    float v1 = fmaxf(a1 + bv.y, 0.f);
    float v2 = fmaxf(a2 + bv.z, 0.f);
    float v3 = fmaxf(a3 + bv.w, 0.f);
    v0 = ((mk >> (sh + 0)) & 1u) ? 0.f : v0 * 2.0f;
    v1 = ((mk >> (sh + 1)) & 1u) ? 0.f : v1 * 2.0f;
    v2 = ((mk >> (sh + 2)) & 1u) ? 0.f : v2 * 2.0f;
    v3 = ((mk >> (sh + 3)) & 1u) ? 0.f : v3 * 2.0f;
    *(float4*)((float*)outp + (size_t)wid * 256 + f0) = make_float4(v0, v1, v2, v3);
  } else {
    uint2 o;
    o.x = (unsigned)f2b(a0) | ((unsigned)f2b(a1) << 16);
    o.y = (unsigned)f2b(a2) | ((unsigned)f2b(a3) << 16);
    *(uint2*)((ushort*)outp + (size_t)wid * 256 + f0) = o;
    // layer-1 mask: lane packs bits for h elements [wid*512 + lane*8, +8)
    {
      unsigned gl = (unsigned)wid * 64u + (unsigned)lane;
      unsigned eb = gl * 8u;
      unsigned byte = 0;
#pragma unroll
      for (int j = 0; j < 8; ++j) {
        U2 r = threefry2x32(k10, k11, 0u, eb + (unsigned)j);
        byte |= (((r.a ^ r.b) >> 31) & 1u) << j;
      }
      mask1Gen[gl] = (unsigned char)byte;
    }
    // layer-2 mask: lanes<32 pack bits for out elements [wid*256 + lane*8, +8)
    if (lane < 32) {
      unsigned eb = (unsigned)wid * 256u + (unsigned)lane * 8u;
      unsigned byte = 0;
#pragma unroll
      for (int j = 0; j < 8; ++j) {
        U2 r = threefry2x32(k20, k21, 0u, eb + (unsigned)j);
        byte |= (((r.a ^ r.b) >> 31) & 1u) << j;
      }
      mask2Gen[(size_t)wid * 32 + lane] = (unsigned char)byte;
    }
  }
}

// ---------------------------------------------------------------------------
// bf16 MFMA GEMM: C[M,N] = A[M,K] @ BT[N,K]^T.  128x128 tile, BK=64, 4 waves,
// single-buffer 32KB staging, XOR-swizzled, swapped-operand mfma (lane holds
// 4 contiguous cols -> direct 8B C stores). 1-D grid, bijective XCD swizzle,
// y (N-strip) fastest so same-A-tile blocks land adjacent on one XCD's L2.
// EPI: bias+relu+mask1-bit dropout.
// ---------------------------------------------------------------------------
template <bool EPI, int NSTRIP>
__global__ __launch_bounds__(256) void gemm_bf16(const ushort* __restrict__ A,
                                                 const ushort* __restrict__ BT,
                                                 ushort* __restrict__ C,
                                                 int M, int K, int N,
                                                 const float* __restrict__ bias,
                                                 const unsigned char* __restrict__ mask1) {
  __shared__ __align__(16) ushort lds[16384];  // A 16KB | B 16KB
  // bijective XCD swizzle (m204): XCD xcd gets a contiguous wg chunk
  const int nwg = gridDim.x;
  {
  }
  const int orig = blockIdx.x;
  const int q = nwg >> 3, r = nwg & 7;
  const int xcd = orig & 7, loc = orig >> 3;
  const int wg = (xcd < r) ? (xcd * (q + 1) + loc)
                           : (r * (q + 1) + (xcd - r) * q + loc);
  const int bm = (wg / NSTRIP) * 128;
  const int bn = (wg % NSTRIP) * 128;

  const int tid = threadIdx.x;
  const int lane = tid & 63;
  const int wv = tid >> 6;
  const int wr = wv >> 1, wc = wv & 1;

  f32x4 acc[4][4] = {};
  const int xorv = (lane & 7) << 4;

  const int nt = K >> 6;
  for (int t = 0; t < nt; ++t) {
    const int k0 = t << 6;
#pragma unroll
    for (int l = 0; l < 4; ++l) {
      int cid = l * 256 + tid;
      int row = cid >> 3;
      int kcol = ((cid & 7) ^ (row & 7)) * 8;
      gload16(A + (size_t)(bm + row) * K + k0 + kcol, (void*)(lds + cid * 8));
      gload16(BT + (size_t)(bn + row) * K + k0 + kcol, (void*)(lds + 8192 + cid * 8));
    }
    __syncthreads();
    const char* Ab = (const char*)lds;
    const char* Bb = (const char*)(lds + 8192);
#pragma unroll
    for (int ks = 0; ks < 2; ++ks) {
      bf16x8 af[4], bf[4];
      const int kb = (ks * 64 + (lane >> 4) * 16) ^ xorv;
#pragma unroll
      for (int i = 0; i < 4; ++i) {
        int arow = wr * 64 + i * 16 + (lane & 15);
        af[i] = *(const bf16x8*)(Ab + arow * 128 + kb);
        int brow = wc * 64 + i * 16 + (lane & 15);
        bf[i] = *(const bf16x8*)(Bb + brow * 128 + kb);
      }
      // swapped operands: D rows <- bf (n), D cols (lane&15... ) <- af (m)
#pragma unroll
      for (int m = 0; m < 4; ++m)
#pragma unroll
        for (int n = 0; n < 4; ++n)
          acc[m][n] = __builtin_amdgcn_mfma_f32_16x16x32_bf16(bf[n], af[m], acc[m][n], 0, 0, 0);
    }
    __syncthreads();
  }

  // epilogue: lane owns C[grow][gcol..gcol+3] per (m,n) -> direct 8B store
  const int growb = bm + wr * 64 + (lane & 15);
  const int gcolb = bn + wc * 64 + ((lane >> 4) << 2);
  float4 bias_v[4];
  if (EPI) {
#pragma unroll
    for (int n = 0; n < 4; ++n) bias_v[n] = *(const float4*)(bias + gcolb + n * 16);
  }
#pragma unroll
  for (int m = 0; m < 4; ++m) {
    int grow = growb + m * 16;
    unsigned long long mrow = 0;
    if (EPI)
      mrow = *(const unsigned long long*)(mask1 + (((size_t)grow * N + bn + wc * 64) >> 3));
#pragma unroll
    for (int n = 0; n < 4; ++n) {
      int gcol = gcolb + n * 16;
      float v[4];
#pragma unroll
      for (int r2 = 0; r2 < 4; ++r2) {
        float x = acc[m][n][r2];
        if (EPI) {
          x = fmaxf(x + ((const float*)&bias_v[n])[r2], 0.f);
          int bit = (gcol - (bn + wc * 64)) + r2;
          x = ((mrow >> bit) & 1ull) ? 0.f : x * 2.0f;
        }
        v[r2] = x;
      }
      uint2 o;
      o.x = (unsigned)f2b(v[0]) | ((unsigned)f2b(v[1]) << 16);
      o.y = (unsigned)f2b(v[2]) | ((unsigned)f2b(v[3]) << 16);
      *(uint2*)(C + (size_t)grow * N + gcol) = o;
    }
  }
}

// ---------------------------------------------------------------------------
extern "C" void kernel_launch(void* const* d_in, const int* in_sizes, int n_in,
                              void* d_out, int out_size, void* d_ws, size_t ws_size,
                              hipStream_t stream) {
  const float* x  = (const float*)d_in[0];
  const int*   ei = (const int*)d_in[1];
  const float* W1 = (const float*)d_in[2];
  const float* b1 = (const float*)d_in[3];
  const float* W2 = (const float*)d_in[4];
  const float* b2 = (const float*)d_in[5];
  float* out = (float*)d_out;
  (void)in_sizes; (void)n_in; (void)out_size; (void)ws_size;

  const int* row = ei;
  const int* col = ei + N_EDGES;

  // workspace layout (bytes)
  char* ws = (char*)d_ws;
  float*  dinv      = (float*) (ws);                           // 200 KB
  int*    cnt       = (int*)   (ws + (1u << 18));              // 200 KB
  int*    indptr    = (int*)   (ws + (2u << 18));              // 200 KB + 4
  int*    cursor    = (int*)   (ws + (3u << 18));              // 200 KB
  int*    chunkSums = (int*)   (ws + (1u << 20));              // tiny
  int2*   srcW      = (int2*)  (ws + 2u * (1u << 20));         // 6.4 MB
  ushort* W1T       = (ushort*)(ws + 9u * (1u << 20));         // 256 KB [512][256]
  ushort* W2T       = (ushort*)(ws + 9u * (1u << 20) + (1u << 19)); // 256 KB
  unsigned char* mask1 = (unsigned char*)(ws + 10u * (1u << 20)); // 3.21 MB
  unsigned char* mask2 = (unsigned char*)(ws + 14u * (1u << 20)); // 1.61 MB
  ushort* x16       = (ushort*)(ws + 18u * (1u << 20));        // 25.6 MB [50000][256]
  ushort* aggB      = (ushort*)(ws + 44u * (1u << 20));        // 25.6 MB [M_PAD][256]
  ushort* h         = (ushort*)(ws + 70u * (1u << 20));        // 51.2 MB [M_PAD][512]
  ushort* hw2       = (ushort*)(ws + 122u* (1u << 20));        // 25.6 MB [M_PAD][256]

  constexpr U2 K1 = threefry2x32(0u, 42u, 0u, 0u);
  constexpr U2 K2 = threefry2x32(0u, 42u, 0u, 1u);

  // ---- CSR build ----
  (void)hipMemsetAsync(cnt, 0, N_NODES * sizeof(int), stream);
  (void)hipMemsetAsync(cursor, 0, N_NODES * sizeof(int), stream);
  deg_kernel<<<(N_EDGES + 255) / 256, 256, 0, stream>>>(col, cnt, N_EDGES);
  const int nChunks = (N_NODES + 1023) / 1024;
  scan_local<<<nChunks, 1024, 0, stream>>>(cnt, indptr, chunkSums, dinv, N_NODES);
  scan_chunks<<<1, 64, 0, stream>>>(chunkSums, nChunks);
  add_offsets<<<(N_NODES + 255) / 256, 256, 0, stream>>>(indptr, chunkSums, N_NODES, N_EDGES);
  build_csr<<<(N_EDGES + 255) / 256, 256, 0, stream>>>(row, col, indptr, cursor, dinv, srcW, N_EDGES);

  // ---- converts ----
  cvt_f32_bf16<<<(N_NODES * IN_C / 4 + 255) / 256, 256, 0, stream>>>(x, x16, N_NODES * IN_C / 4);
  wT_both<<<(IN_C * HID_C + HID_C * OUT_C + 255) / 256, 256, 0, stream>>>(W1, W2, W1T, W2T);
  (void)hipMemsetAsync(aggB + (size_t)N_NODES * IN_C, 0, (size_t)(M_PAD - N_NODES) * IN_C * 2, stream);

  // ---- layer 1 ----
  gather8<false><<<(N_NODES + 3) / 4, 256, 0, stream>>>(
      x16, indptr, srcW, dinv, nullptr, aggB, mask1, mask2, nullptr,
      K1.a, K1.b, K2.a, K2.b, N_NODES);
  gemm_bf16<true, HID_C / 128><<<(M_PAD / 128) * (HID_C / 128), 256, 0, stream>>>(
      aggB, W1T, h, M_PAD, IN_C, HID_C, b1, mask1);

  // ---- layer 2 ----
  gemm_bf16<false, OUT_C / 128><<<(M_PAD / 128) * (OUT_C / 128), 256, 0, stream>>>(
      h, W2T, hw2, M_PAD, HID_C, OUT_C, nullptr, nullptr);
  gather8<true><<<(N_NODES + 3) / 4, 256, 0, stream>>>(
      hw2, indptr, srcW, dinv, b2, out, nullptr, nullptr, mask2,
      0u, 0u, 0u, 0u, N_NODES);
}

// Round 12
// 332.045 us; speedup vs baseline: 1.0816x; 1.0816x over previous
//
#include <hip/hip_runtime.h>
#include <stdint.h>

// ---------------------------------------------------------------------------
// GCN: agg1 = A_hat x (8-deep gather + mask1 bitmap only)
//      h    = relu+drop(agg1 W1 + b1)   (MFMA GEMM, mask1 bit-test)
//      hw2  = h W2                      (MFMA GEMM, plain)
//      out  = relu+drop(A_hat hw2 + b2) (8-deep gather + mask2 bit-test)
// mask2 is generated inside the memory-bound cvt kernel (VALU headroom).
// GEMMs: swapped-operand MFMA (direct 8B C stores), single-buffer 32KB LDS,
// 1-D grid with bijective XCD swizzle (N-strip fastest) for A/W L2 reuse.
// ---------------------------------------------------------------------------

#define N_NODES 50000
#define N_EDGES 800000
#define M_PAD   50048   // 391 * 128
#define IN_C 256
#define HID_C 512
#define OUT_C 256

typedef __attribute__((ext_vector_type(8))) short bf16x8;
typedef __attribute__((ext_vector_type(4))) float f32x4;

struct U2 { unsigned a, b; };

__host__ __device__ constexpr unsigned rotl32(unsigned x, int d) {
  return (x << d) | (x >> (32 - d));
}

#define TF_ROUND(r) { x0 += x1; x1 = rotl32(x1, (r)); x1 ^= x0; }

__host__ __device__ constexpr U2 threefry2x32(unsigned k0, unsigned k1,
                                              unsigned x0, unsigned x1) {
  unsigned ks2 = k0 ^ k1 ^ 0x1BD11BDAu;
  x0 += k0; x1 += k1;
  TF_ROUND(13) TF_ROUND(15) TF_ROUND(26) TF_ROUND(6)  x0 += k1;  x1 += ks2 + 1u;
  TF_ROUND(17) TF_ROUND(29) TF_ROUND(16) TF_ROUND(24) x0 += ks2; x1 += k0 + 2u;
  TF_ROUND(13) TF_ROUND(15) TF_ROUND(26) TF_ROUND(6)  x0 += k0;  x1 += k1 + 3u;
  TF_ROUND(17) TF_ROUND(29) TF_ROUND(16) TF_ROUND(24) x0 += k1;  x1 += ks2 + 4u;
  TF_ROUND(13) TF_ROUND(15) TF_ROUND(26) TF_ROUND(6)  x0 += ks2; x1 += k0 + 5u;
  return U2{x0, x1};
}

__device__ __forceinline__ ushort f2b(float f) {  // RTNE
  unsigned u = __builtin_bit_cast(unsigned, f);
  unsigned r = (u + 0x7fffu + ((u >> 16) & 1u)) >> 16;
  return (ushort)r;
}
__device__ __forceinline__ float b2f(ushort h) {
  unsigned u = (unsigned)h << 16;
  return __builtin_bit_cast(float, u);
}

__device__ __forceinline__ void gload16(const void* g, void* l) {
  __builtin_amdgcn_global_load_lds(
      (const __attribute__((address_space(1))) void*)g,
      (__attribute__((address_space(3))) void*)l, 16, 0, 0);
}

// ---------------------------------------------------------------------------
// degree / scan(+dinv) / CSR build (CSR entry = {src, dinv[src]})
// ---------------------------------------------------------------------------
__global__ void deg_kernel(const int* __restrict__ col, int* __restrict__ cnt, int E) {
  int e = blockIdx.x * 256 + threadIdx.x;
  if (e < E) atomicAdd(&cnt[col[e]], 1);
}

__global__ __launch_bounds__(1024) void scan_local(const int* __restrict__ cnt,
                                                   int* __restrict__ indptr,
                                                   int* __restrict__ chunkSums,
                                                   float* __restrict__ dinv, int n) {
  __shared__ int s[1024];
  int gid = blockIdx.x * 1024 + threadIdx.x;
  int v = (gid < n) ? cnt[gid] : 0;
  if (gid < n) dinv[gid] = rsqrtf((float)v + 1.0f);
  s[threadIdx.x] = v;
  __syncthreads();
#pragma unroll
  for (int off = 1; off < 1024; off <<= 1) {
    int t = (threadIdx.x >= off) ? s[threadIdx.x - off] : 0;
    __syncthreads();
    s[threadIdx.x] += t;
    __syncthreads();
  }
  if (gid < n) indptr[gid] = s[threadIdx.x] - v;
  if (threadIdx.x == 1023) chunkSums[blockIdx.x] = s[1023];
}

__global__ void scan_chunks(int* __restrict__ chunkSums, int nChunks) {
  if (threadIdx.x == 0 && blockIdx.x == 0) {
    int acc = 0;
    for (int i = 0; i < nChunks; ++i) { int t = chunkSums[i]; chunkSums[i] = acc; acc += t; }
  }
}

__global__ void add_offsets(int* __restrict__ indptr, const int* __restrict__ chunkSums,
                            int n, int total) {
  int gid = blockIdx.x * 256 + threadIdx.x;
  if (gid < n) indptr[gid] += chunkSums[gid >> 10];
  if (gid == 0) indptr[n] = total;
}

__global__ void build_csr(const int* __restrict__ row, const int* __restrict__ col,
                          const int* __restrict__ indptr, int* __restrict__ cursor,
                          const float* __restrict__ dinv,
                          int2* __restrict__ srcW, int E) {
  int e = blockIdx.x * 256 + threadIdx.x;
  if (e < E) {
    int r = row[e];
    int c = col[e];
    int p = indptr[c] + atomicAdd(&cursor[c], 1);
    srcW[p] = make_int2(r, __builtin_bit_cast(int, dinv[r]));
  }
}

// ---------------------------------------------------------------------------
// converts. cvt also generates the layer-2 dropout bitmask (threefry hides
// under the streaming copy's memory wall).
// ---------------------------------------------------------------------------
__global__ void cvt_f32_bf16(const float* __restrict__ in, ushort* __restrict__ out,
                             int n4, unsigned char* __restrict__ mask2,
                             unsigned k20, unsigned k21, int nMaskBytes) {
  int i = blockIdx.x * 256 + threadIdx.x;
  if (i < n4) {
    float4 v = *(const float4*)(in + (size_t)i * 4);
    ushort4 o = make_ushort4(f2b(v.x), f2b(v.y), f2b(v.z), f2b(v.w));
    *(ushort4*)(out + (size_t)i * 4) = o;
  }
  if (i < nMaskBytes) {
    unsigned eb = (unsigned)i * 8u;
    unsigned byte = 0;
#pragma unroll
    for (int j = 0; j < 8; ++j) {
      U2 r = threefry2x32(k20, k21, 0u, eb + (unsigned)j);
      byte |= (((r.a ^ r.b) >> 31) & 1u) << j;
    }
    mask2[i] = (unsigned char)byte;
  }
}

// W1T[n][k]=bf16(W1[k][n]) (256x512) and W2T[n][k]=bf16(W2[k][n]) (512x256)
__global__ void wT_both(const float* __restrict__ W1, const float* __restrict__ W2,
                        ushort* __restrict__ W1T, ushort* __restrict__ W2T) {
  int i = blockIdx.x * 256 + threadIdx.x;
  if (i < IN_C * HID_C) {
    int k = i & (IN_C - 1);
    int n = i >> 8;
    W1T[i] = f2b(W1[(size_t)k * HID_C + n]);
  } else {
    int j = i - IN_C * HID_C;
    int k = j & (HID_C - 1);
    int n = j >> 9;
    W2T[j] = f2b(W2[(size_t)k * OUT_C + n]);
  }
}

// ---------------------------------------------------------------------------
// gather over CSR pairs: one wave per node, 64 lanes x 8B, 8-deep unrolled.
// EPI=false: bf16 out + mask1 bitmap (8 threefry/lane — proven free here).
// EPI=true:  bias+relu+mask2-bit dropout, fp32 out.
// ---------------------------------------------------------------------------
#define ROW_ACC(vv, ww)                                                        \
  { a0 += b2f((vv).x) * (ww); a1 += b2f((vv).y) * (ww);                        \
    a2 += b2f((vv).z) * (ww); a3 += b2f((vv).w) * (ww); }

template <bool EPI>
__global__ __launch_bounds__(256) void gather8(const ushort* __restrict__ X,
                                               const int* __restrict__ indptr,
                                               const int2* __restrict__ srcW,
                                               const float* __restrict__ dinv,
                                               const float* __restrict__ bias,
                                               void* __restrict__ outp,
                                               unsigned char* __restrict__ mask1Gen,
                                               const unsigned char* __restrict__ maskUse,
                                               unsigned k10, unsigned k11, int N) {
  int wid = (blockIdx.x * 256 + threadIdx.x) >> 6;
  int lane = threadIdx.x & 63;
  if (wid >= N) return;
  int beg = __builtin_amdgcn_readfirstlane(indptr[wid]);
  int end = __builtin_amdgcn_readfirstlane(indptr[wid + 1]);
  float dc = dinv[wid];
  const int f0 = lane * 4;
  ushort4 sv = *(const ushort4*)(X + (size_t)wid * 256 + f0);
  float a0 = b2f(sv.x) * dc, a1 = b2f(sv.y) * dc,
        a2 = b2f(sv.z) * dc, a3 = b2f(sv.w) * dc;

  int e = beg;
  for (; e + 8 <= end; e += 8) {
    int2 p0 = srcW[e + 0], p1 = srcW[e + 1], p2 = srcW[e + 2], p3 = srcW[e + 3];
    int2 p4 = srcW[e + 4], p5 = srcW[e + 5], p6 = srcW[e + 6], p7 = srcW[e + 7];
    ushort4 v0 = *(const ushort4*)(X + (size_t)p0.x * 256 + f0);
    ushort4 v1 = *(const ushort4*)(X + (size_t)p1.x * 256 + f0);
    ushort4 v2 = *(const ushort4*)(X + (size_t)p2.x * 256 + f0);
    ushort4 v3 = *(const ushort4*)(X + (size_t)p3.x * 256 + f0);
    ushort4 v4 = *(const ushort4*)(X + (size_t)p4.x * 256 + f0);
    ushort4 v5 = *(const ushort4*)(X + (size_t)p5.x * 256 + f0);
    ushort4 v6 = *(const ushort4*)(X + (size_t)p6.x * 256 + f0);
    ushort4 v7 = *(const ushort4*)(X + (size_t)p7.x * 256 + f0);
    ROW_ACC(v0, __builtin_bit_cast(float, p0.y));
    ROW_ACC(v1, __builtin_bit_cast(float, p1.y));
    ROW_ACC(v2, __builtin_bit_cast(float, p2.y));
    ROW_ACC(v3, __builtin_bit_cast(float, p3.y));
    ROW_ACC(v4, __builtin_bit_cast(float, p4.y));
    ROW_ACC(v5, __builtin_bit_cast(float, p5.y));
    ROW_ACC(v6, __builtin_bit_cast(float, p6.y));
    ROW_ACC(v7, __builtin_bit_cast(float, p7.y));
  }
  for (; e + 2 <= end; e += 2) {
    int2 p0 = srcW[e + 0], p1 = srcW[e + 1];
    ushort4 v0 = *(const ushort4*)(X + (size_t)p0.x * 256 + f0);
    ushort4 v1 = *(const ushort4*)(X + (size_t)p1.x * 256 + f0);
    ROW_ACC(v0, __builtin_bit_cast(float, p0.y));
    ROW_ACC(v1, __builtin_bit_cast(float, p1.y));
  }
  if (e < end) {
    int2 p0 = srcW[e];
    ushort4 v0 = *(const ushort4*)(X + (size_t)p0.x * 256 + f0);
    ROW_ACC(v0, __builtin_bit_cast(float, p0.y));
  }
  a0 *= dc; a1 *= dc; a2 *= dc; a3 *= dc;

  if (EPI) {
    float4 bv = *(const float4*)(bias + f0);
    unsigned mk = maskUse[(size_t)wid * 32 + (lane >> 1)];
    int sh = (lane & 1) * 4;
    float v0 = fmaxf(a0 + bv.x, 0.f);
    float v1 = fmaxf(a1 + bv.y, 0.f);
    float v2 = fmaxf(a2 + bv.z, 0.f);
    float v3 = fmaxf(a3 + bv.w, 0.f);
    v0 = ((mk >> (sh + 0)) & 1u) ? 0.f : v0 * 2.0f;
    v1 = ((mk >> (sh + 1)) & 1u) ? 0.f : v1 * 2.0f;
    v2 = ((mk >> (sh + 2)) & 1u) ? 0.f : v2 * 2.0f;
    v3 = ((mk >> (sh + 3)) & 1u) ? 0.f : v3 * 2.0f;
    *(float4*)((float*)outp + (size_t)wid * 256 + f0) = make_float4(v0, v1, v2, v3);
  } else {
    uint2 o;
    o.x = (unsigned)f2b(a0) | ((unsigned)f2b(a1) << 16);
    o.y = (unsigned)f2b(a2) | ((unsigned)f2b(a3) << 16);
    *(uint2*)((ushort*)outp + (size_t)wid * 256 + f0) = o;
    // layer-1 mask: lane packs bits for h elements [gl*8, gl*8+8)
    unsigned gl = (unsigned)wid * 64u + (unsigned)lane;
    unsigned eb = gl * 8u;
    unsigned byte = 0;
#pragma unroll
    for (int j = 0; j < 8; ++j) {
      U2 r = threefry2x32(k10, k11, 0u, eb + (unsigned)j);
      byte |= (((r.a ^ r.b) >> 31) & 1u) << j;
    }
    mask1Gen[gl] = (unsigned char)byte;
  }
}

// ---------------------------------------------------------------------------
// bf16 MFMA GEMM: C[M,N] = A[M,K] @ BT[N,K]^T.  128x128 tile, BK=64, 4 waves,
// single-buffer 32KB staging, XOR-swizzled, swapped-operand mfma (lane holds
// 4 contiguous cols -> direct 8B C stores). 1-D grid, bijective XCD swizzle,
// N-strip fastest so same-A-tile blocks land adjacent on one XCD's L2.
// EPI: bias+relu+mask1-bit dropout.
// ---------------------------------------------------------------------------
template <bool EPI, int NSTRIP>
__global__ __launch_bounds__(256) void gemm_bf16(const ushort* __restrict__ A,
                                                 const ushort* __restrict__ BT,
                                                 ushort* __restrict__ C,
                                                 int M, int K, int N,
                                                 const float* __restrict__ bias,
                                                 const unsigned char* __restrict__ mask1) {
  __shared__ __align__(16) ushort lds[16384];  // A 16KB | B 16KB
  // bijective XCD swizzle (m204): each XCD gets a contiguous wg chunk
  const int nwg = gridDim.x;
  const int orig = blockIdx.x;
  const int q = nwg >> 3, r = nwg & 7;
  const int xcd = orig & 7, loc = orig >> 3;
  const int wg = (xcd < r) ? (xcd * (q + 1) + loc)
                           : (r * (q + 1) + (xcd - r) * q + loc);
  const int bm = (wg / NSTRIP) * 128;
  const int bn = (wg % NSTRIP) * 128;

  const int tid = threadIdx.x;
  const int lane = tid & 63;
  const int wv = tid >> 6;
  const int wr = wv >> 1, wc = wv & 1;

  f32x4 acc[4][4] = {};
  const int xorv = (lane & 7) << 4;

  const int nt = K >> 6;
  for (int t = 0; t < nt; ++t) {
    const int k0 = t << 6;
#pragma unroll
    for (int l = 0; l < 4; ++l) {
      int cid = l * 256 + tid;
      int row = cid >> 3;
      int kcol = ((cid & 7) ^ (row & 7)) * 8;
      gload16(A + (size_t)(bm + row) * K + k0 + kcol, (void*)(lds + cid * 8));
      gload16(BT + (size_t)(bn + row) * K + k0 + kcol, (void*)(lds + 8192 + cid * 8));
    }
    __syncthreads();
    const char* Ab = (const char*)lds;
    const char* Bb = (const char*)(lds + 8192);
#pragma unroll
    for (int ks = 0; ks < 2; ++ks) {
      bf16x8 af[4], bf[4];
      const int kb = (ks * 64 + (lane >> 4) * 16) ^ xorv;
#pragma unroll
      for (int i = 0; i < 4; ++i) {
        int arow = wr * 64 + i * 16 + (lane & 15);
        af[i] = *(const bf16x8*)(Ab + arow * 128 + kb);
        int brow = wc * 64 + i * 16 + (lane & 15);
        bf[i] = *(const bf16x8*)(Bb + brow * 128 + kb);
      }
      // swapped operands: D rows <- bf (n), D cols <- af (m)
#pragma unroll
      for (int m = 0; m < 4; ++m)
#pragma unroll
        for (int n = 0; n < 4; ++n)
          acc[m][n] = __builtin_amdgcn_mfma_f32_16x16x32_bf16(bf[n], af[m], acc[m][n], 0, 0, 0);
    }
    __syncthreads();
  }

  // epilogue: lane owns C[grow][gcol..gcol+3] per (m,n) -> direct 8B store
  const int growb = bm + wr * 64 + (lane & 15);
  const int gcolb = bn + wc * 64 + ((lane >> 4) << 2);
  float4 bias_v[4];
  if (EPI) {
#pragma unroll
    for (int n = 0; n < 4; ++n) bias_v[n] = *(const float4*)(bias + gcolb + n * 16);
  }
#pragma unroll
  for (int m = 0; m < 4; ++m) {
    int grow = growb + m * 16;
    unsigned long long mrow = 0;
    if (EPI)
      mrow = *(const unsigned long long*)(mask1 + (((size_t)grow * N + bn + wc * 64) >> 3));
#pragma unroll
    for (int n = 0; n < 4; ++n) {
      int gcol = gcolb + n * 16;
      float v[4];
#pragma unroll
      for (int r2 = 0; r2 < 4; ++r2) {
        float x = acc[m][n][r2];
        if (EPI) {
          x = fmaxf(x + ((const float*)&bias_v[n])[r2], 0.f);
          int bit = (gcol - (bn + wc * 64)) + r2;
          x = ((mrow >> bit) & 1ull) ? 0.f : x * 2.0f;
        }
        v[r2] = x;
      }
      uint2 o;
      o.x = (unsigned)f2b(v[0]) | ((unsigned)f2b(v[1]) << 16);
      o.y = (unsigned)f2b(v[2]) | ((unsigned)f2b(v[3]) << 16);
      *(uint2*)(C + (size_t)grow * N + gcol) = o;
    }
  }
}

// ---------------------------------------------------------------------------
extern "C" void kernel_launch(void* const* d_in, const int* in_sizes, int n_in,
                              void* d_out, int out_size, void* d_ws, size_t ws_size,
                              hipStream_t stream) {
  const float* x  = (const float*)d_in[0];
  const int*   ei = (const int*)d_in[1];
  const float* W1 = (const float*)d_in[2];
  const float* b1 = (const float*)d_in[3];
  const float* W2 = (const float*)d_in[4];
  const float* b2 = (const float*)d_in[5];
  float* out = (float*)d_out;
  (void)in_sizes; (void)n_in; (void)out_size; (void)ws_size;

  const int* row = ei;
  const int* col = ei + N_EDGES;

  // workspace layout (bytes)
  char* ws = (char*)d_ws;
  float*  dinv      = (float*) (ws);                           // 200 KB
  int*    cnt       = (int*)   (ws + (1u << 18));              // 200 KB
  int*    cursor    = (int*)   (ws + (2u << 18));              // 200 KB (adjacent to cnt)
  int*    indptr    = (int*)   (ws + (3u << 18));              // 200 KB + 4
  int*    chunkSums = (int*)   (ws + (1u << 20));              // tiny
  int2*   srcW      = (int2*)  (ws + 2u * (1u << 20));         // 6.4 MB
  ushort* W1T       = (ushort*)(ws + 9u * (1u << 20));         // 256 KB [512][256]
  ushort* W2T       = (ushort*)(ws + 9u * (1u << 20) + (1u << 19)); // 256 KB
  unsigned char* mask1 = (unsigned char*)(ws + 10u * (1u << 20)); // 3.21 MB
  unsigned char* mask2 = (unsigned char*)(ws + 14u * (1u << 20)); // 1.61 MB
  ushort* x16       = (ushort*)(ws + 18u * (1u << 20));        // 25.6 MB [50000][256]
  ushort* aggB      = (ushort*)(ws + 44u * (1u << 20));        // 25.6 MB [M_PAD][256]
  ushort* h         = (ushort*)(ws + 70u * (1u << 20));        // 51.2 MB [M_PAD][512]
  ushort* hw2       = (ushort*)(ws + 122u* (1u << 20));        // 25.6 MB [M_PAD][256]

  constexpr U2 K1 = threefry2x32(0u, 42u, 0u, 0u);
  constexpr U2 K2 = threefry2x32(0u, 42u, 0u, 1u);

  // ---- CSR build ----
  (void)hipMemsetAsync(cnt, 0, 2u * (1u << 18), stream);  // cnt + cursor
  deg_kernel<<<(N_EDGES + 255) / 256, 256, 0, stream>>>(col, cnt, N_EDGES);
  const int nChunks = (N_NODES + 1023) / 1024;
  scan_local<<<nChunks, 1024, 0, stream>>>(cnt, indptr, chunkSums, dinv, N_NODES);
  scan_chunks<<<1, 64, 0, stream>>>(chunkSums, nChunks);
  add_offsets<<<(N_NODES + 255) / 256, 256, 0, stream>>>(indptr, chunkSums, N_NODES, N_EDGES);
  build_csr<<<(N_EDGES + 255) / 256, 256, 0, stream>>>(row, col, indptr, cursor, dinv, srcW, N_EDGES);

  // ---- converts (cvt also generates mask2) ----
  cvt_f32_bf16<<<(N_NODES * IN_C / 4 + 255) / 256, 256, 0, stream>>>(
      x, x16, N_NODES * IN_C / 4, mask2, K2.a, K2.b, N_NODES * 32);
  wT_both<<<(IN_C * HID_C + HID_C * OUT_C + 255) / 256, 256, 0, stream>>>(W1, W2, W1T, W2T);
  (void)hipMemsetAsync(aggB + (size_t)N_NODES * IN_C, 0, (size_t)(M_PAD - N_NODES) * IN_C * 2, stream);

  // ---- layer 1 ----
  gather8<false><<<(N_NODES + 3) / 4, 256, 0, stream>>>(
      x16, indptr, srcW, dinv, nullptr, aggB, mask1, nullptr, K1.a, K1.b, N_NODES);
  gemm_bf16<true, HID_C / 128><<<(M_PAD / 128) * (HID_C / 128), 256, 0, stream>>>(
      aggB, W1T, h, M_PAD, IN_C, HID_C, b1, mask1);

  // ---- layer 2 ----
  gemm_bf16<false, OUT_C / 128><<<(M_PAD / 128) * (OUT_C / 128), 256, 0, stream>>>(
      h, W2T, hw2, M_PAD, HID_C, OUT_C, nullptr, nullptr);
  gather8<true><<<(N_NODES + 3) / 4, 256, 0, stream>>>(
      hw2, indptr, srcW, dinv, b2, out, nullptr, mask2, 0u, 0u, N_NODES);
}

// Round 13
// 322.921 us; speedup vs baseline: 1.1122x; 1.0283x over previous
//
#include <hip/hip_runtime.h>
#include <stdint.h>

// ---------------------------------------------------------------------------
// GCN: agg1 = A_hat x (8-deep gather + mask1 bitmap)
//      h    = relu+drop(agg1 W1 + b1)   (MFMA GEMM, mask1 bit-test)
//      hw2  = h W2                      (MFMA GEMM, plain)
//      out  = relu+drop(A_hat hw2 + b2) (8-deep gather + mask2 bit-test)
// mask2 generated in the streaming prep kernel (VALU headroom).
// CSR entries carry {src_byte_offset, dinv[src]} so the gather row address is
// a single 32-bit add. Prologue consolidated: 10 launches total.
// ---------------------------------------------------------------------------

#define N_NODES 50000
#define N_EDGES 800000
#define M_PAD   50048   // 391 * 128
#define IN_C 256
#define HID_C 512
#define OUT_C 256

typedef __attribute__((ext_vector_type(8))) short bf16x8;
typedef __attribute__((ext_vector_type(4))) float f32x4;

struct U2 { unsigned a, b; };

__host__ __device__ constexpr unsigned rotl32(unsigned x, int d) {
  return (x << d) | (x >> (32 - d));
}

#define TF_ROUND(r) { x0 += x1; x1 = rotl32(x1, (r)); x1 ^= x0; }

__host__ __device__ constexpr U2 threefry2x32(unsigned k0, unsigned k1,
                                              unsigned x0, unsigned x1) {
  unsigned ks2 = k0 ^ k1 ^ 0x1BD11BDAu;
  x0 += k0; x1 += k1;
  TF_ROUND(13) TF_ROUND(15) TF_ROUND(26) TF_ROUND(6)  x0 += k1;  x1 += ks2 + 1u;
  TF_ROUND(17) TF_ROUND(29) TF_ROUND(16) TF_ROUND(24) x0 += ks2; x1 += k0 + 2u;
  TF_ROUND(13) TF_ROUND(15) TF_ROUND(26) TF_ROUND(6)  x0 += k0;  x1 += k1 + 3u;
  TF_ROUND(17) TF_ROUND(29) TF_ROUND(16) TF_ROUND(24) x0 += k1;  x1 += ks2 + 4u;
  TF_ROUND(13) TF_ROUND(15) TF_ROUND(26) TF_ROUND(6)  x0 += ks2; x1 += k0 + 5u;
  return U2{x0, x1};
}

__device__ __forceinline__ ushort f2b(float f) {  // RTNE
  unsigned u = __builtin_bit_cast(unsigned, f);
  unsigned r = (u + 0x7fffu + ((u >> 16) & 1u)) >> 16;
  return (ushort)r;
}
__device__ __forceinline__ float b2f(ushort h) {
  unsigned u = (unsigned)h << 16;
  return __builtin_bit_cast(float, u);
}

__device__ __forceinline__ void gload16(const void* g, void* l) {
  __builtin_amdgcn_global_load_lds(
      (const __attribute__((address_space(1))) void*)g,
      (__attribute__((address_space(3))) void*)l, 16, 0, 0);
}

// ---------------------------------------------------------------------------
// degree / scan(+dinv) / merged chunk-scan+add / CSR build
// CSR entry = {src*512 (byte offset), dinv[src]}
// ---------------------------------------------------------------------------
__global__ void deg_kernel(const int* __restrict__ col, int* __restrict__ cnt, int E) {
  int e = blockIdx.x * 256 + threadIdx.x;
  if (e < E) atomicAdd(&cnt[col[e]], 1);
}

__global__ __launch_bounds__(1024) void scan_local(const int* __restrict__ cnt,
                                                   int* __restrict__ indptr,
                                                   int* __restrict__ chunkSums,
                                                   float* __restrict__ dinv, int n) {
  __shared__ int s[1024];
  int gid = blockIdx.x * 1024 + threadIdx.x;
  int v = (gid < n) ? cnt[gid] : 0;
  if (gid < n) dinv[gid] = rsqrtf((float)v + 1.0f);
  s[threadIdx.x] = v;
  __syncthreads();
#pragma unroll
  for (int off = 1; off < 1024; off <<= 1) {
    int t = (threadIdx.x >= off) ? s[threadIdx.x - off] : 0;
    __syncthreads();
    s[threadIdx.x] += t;
    __syncthreads();
  }
  if (gid < n) indptr[gid] = s[threadIdx.x] - v;
  if (threadIdx.x == 1023) chunkSums[blockIdx.x] = s[1023];
}

// merged: first wave shfl-scans the <=64 chunk sums; all threads add offset.
__global__ void scan_add(int* __restrict__ indptr, const int* __restrict__ chunkSums,
                         int n, int nChunks, int total) {
  __shared__ int sc[64];
  int gid = blockIdx.x * 256 + threadIdx.x;
  if (threadIdx.x < 64) {
    int lane = threadIdx.x;
    int v = (lane < nChunks) ? chunkSums[lane] : 0;
    int incl = v;
#pragma unroll
    for (int off = 1; off < 64; off <<= 1) {
      int t = __shfl_up(incl, off);
      if (lane >= off) incl += t;
    }
    sc[lane] = incl - v;  // exclusive prefix
  }
  __syncthreads();
  if (gid < n) indptr[gid] += sc[gid >> 10];
  if (gid == 0) indptr[n] = total;
}

__global__ void build_csr(const int* __restrict__ row, const int* __restrict__ col,
                          const int* __restrict__ indptr, int* __restrict__ cursor,
                          const float* __restrict__ dinv,
                          int2* __restrict__ srcW, int E) {
  int e = blockIdx.x * 256 + threadIdx.x;
  if (e < E) {
    int r = row[e];
    int c = col[e];
    int p = indptr[c] + atomicAdd(&cursor[c], 1);
    srcW[p] = make_int2(r << 9, __builtin_bit_cast(int, dinv[r]));  // byte offset
  }
}

// ---------------------------------------------------------------------------
// prep: x->bf16 cvt, mask2 bitmap gen, W1T/W2T transpose-cvt, aggB pad zero.
// All independent elementwise ranges under one grid (threefry hides under
// the 77MB streaming copy's memory wall).
// ---------------------------------------------------------------------------
__global__ void prep(const float* __restrict__ x, ushort* __restrict__ x16, int n4,
                     unsigned char* __restrict__ mask2,
                     unsigned k20, unsigned k21, int nMaskBytes,
                     const float* __restrict__ W1, const float* __restrict__ W2,
                     ushort* __restrict__ W1T, ushort* __restrict__ W2T,
                     ushort* __restrict__ padDst) {
  int i = blockIdx.x * 256 + threadIdx.x;
  if (i < n4) {
    float4 v = *(const float4*)(x + (size_t)i * 4);
    ushort4 o = make_ushort4(f2b(v.x), f2b(v.y), f2b(v.z), f2b(v.w));
    *(ushort4*)(x16 + (size_t)i * 4) = o;
  }
  if (i < nMaskBytes) {
    unsigned eb = (unsigned)i * 8u;
    unsigned byte = 0;
#pragma unroll
    for (int j = 0; j < 8; ++j) {
      U2 r = threefry2x32(k20, k21, 0u, eb + (unsigned)j);
      byte |= (((r.a ^ r.b) >> 31) & 1u) << j;
    }
    mask2[i] = (unsigned char)byte;
  }
  if (i < IN_C * HID_C) {        // W1T[n][k] = bf16(W1[k][n])
    int k = i & (IN_C - 1);
    int n = i >> 8;
    W1T[i] = f2b(W1[(size_t)k * HID_C + n]);
  } else if (i < IN_C * HID_C + HID_C * OUT_C) {
    int j = i - IN_C * HID_C;    // W2T[n][k] = bf16(W2[k][n])
    int k = j & (HID_C - 1);
    int n = j >> 9;
    W2T[j] = f2b(W2[(size_t)k * OUT_C + n]);
  }
  if (i < (M_PAD - N_NODES) * IN_C / 8) {  // zero pad rows of aggB
    uint4 z = {0u, 0u, 0u, 0u};
    *(uint4*)(padDst + (size_t)i * 8) = z;
  }
}

// ---------------------------------------------------------------------------
// gather over CSR pairs: one wave per node, 64 lanes x 8B, 8-deep unrolled.
// Row address = per-lane base + 32-bit byte offset from srcW.
// EPI=false: bf16 out + mask1 bitmap (8 threefry/lane — proven free here).
// EPI=true:  bias+relu+mask2-bit dropout, fp32 out.
// ---------------------------------------------------------------------------
#define ROW_ACC(vv, ww)                                                        \
  { a0 += b2f((vv).x) * (ww); a1 += b2f((vv).y) * (ww);                        \
    a2 += b2f((vv).z) * (ww); a3 += b2f((vv).w) * (ww); }

template <bool EPI>
__global__ __launch_bounds__(256) void gather8(const ushort* __restrict__ X,
                                               const int* __restrict__ indptr,
                                               const int2* __restrict__ srcW,
                                               const float* __restrict__ dinv,
                                               const float* __restrict__ bias,
                                               void* __restrict__ outp,
                                               unsigned char* __restrict__ mask1Gen,
                                               const unsigned char* __restrict__ maskUse,
                                               unsigned k10, unsigned k11, int N) {
  int wid = (blockIdx.x * 256 + threadIdx.x) >> 6;
  int lane = threadIdx.x & 63;
  if (wid >= N) return;
  int beg = __builtin_amdgcn_readfirstlane(indptr[wid]);
  int end = __builtin_amdgcn_readfirstlane(indptr[wid + 1]);
  float dc = dinv[wid];
  const int f0 = lane * 4;
  const char* Xb = (const char*)X + (unsigned)(lane * 8);  // per-lane base
  ushort4 sv = *(const ushort4*)(Xb + ((size_t)wid << 9));
  float a0 = b2f(sv.x) * dc, a1 = b2f(sv.y) * dc,
        a2 = b2f(sv.z) * dc, a3 = b2f(sv.w) * dc;

  int e = beg;
  for (; e + 8 <= end; e += 8) {
    int2 p0 = srcW[e + 0], p1 = srcW[e + 1], p2 = srcW[e + 2], p3 = srcW[e + 3];
    int2 p4 = srcW[e + 4], p5 = srcW[e + 5], p6 = srcW[e + 6], p7 = srcW[e + 7];
    ushort4 v0 = *(const ushort4*)(Xb + (unsigned)p0.x);
    ushort4 v1 = *(const ushort4*)(Xb + (unsigned)p1.x);
    ushort4 v2 = *(const ushort4*)(Xb + (unsigned)p2.x);
    ushort4 v3 = *(const ushort4*)(Xb + (unsigned)p3.x);
    ushort4 v4 = *(const ushort4*)(Xb + (unsigned)p4.x);
    ushort4 v5 = *(const ushort4*)(Xb + (unsigned)p5.x);
    ushort4 v6 = *(const ushort4*)(Xb + (unsigned)p6.x);
    ushort4 v7 = *(const ushort4*)(Xb + (unsigned)p7.x);
    ROW_ACC(v0, __builtin_bit_cast(float, p0.y));
    ROW_ACC(v1, __builtin_bit_cast(float, p1.y));
    ROW_ACC(v2, __builtin_bit_cast(float, p2.y));
    ROW_ACC(v3, __builtin_bit_cast(float, p3.y));
    ROW_ACC(v4, __builtin_bit_cast(float, p4.y));
    ROW_ACC(v5, __builtin_bit_cast(float, p5.y));
    ROW_ACC(v6, __builtin_bit_cast(float, p6.y));
    ROW_ACC(v7, __builtin_bit_cast(float, p7.y));
  }
  for (; e + 2 <= end; e += 2) {
    int2 p0 = srcW[e + 0], p1 = srcW[e + 1];
    ushort4 v0 = *(const ushort4*)(Xb + (unsigned)p0.x);
    ushort4 v1 = *(const ushort4*)(Xb + (unsigned)p1.x);
    ROW_ACC(v0, __builtin_bit_cast(float, p0.y));
    ROW_ACC(v1, __builtin_bit_cast(float, p1.y));
  }
  if (e < end) {
    int2 p0 = srcW[e];
    ushort4 v0 = *(const ushort4*)(Xb + (unsigned)p0.x);
    ROW_ACC(v0, __builtin_bit_cast(float, p0.y));
  }
  a0 *= dc; a1 *= dc; a2 *= dc; a3 *= dc;

  if (EPI) {
    float4 bv = *(const float4*)(bias + f0);
    unsigned mk = maskUse[(size_t)wid * 32 + (lane >> 1)];
    int sh = (lane & 1) * 4;
    float v0 = fmaxf(a0 + bv.x, 0.f);
    float v1 = fmaxf(a1 + bv.y, 0.f);
    float v2 = fmaxf(a2 + bv.z, 0.f);
    float v3 = fmaxf(a3 + bv.w, 0.f);
    v0 = ((mk >> (sh + 0)) & 1u) ? 0.f : v0 * 2.0f;
    v1 = ((mk >> (sh + 1)) & 1u) ? 0.f : v1 * 2.0f;
    v2 = ((mk >> (sh + 2)) & 1u) ? 0.f : v2 * 2.0f;
    v3 = ((mk >> (sh + 3)) & 1u) ? 0.f : v3 * 2.0f;
    *(float4*)((float*)outp + (size_t)wid * 256 + f0) = make_float4(v0, v1, v2, v3);
  } else {
    uint2 o;
    o.x = (unsigned)f2b(a0) | ((unsigned)f2b(a1) << 16);
    o.y = (unsigned)f2b(a2) | ((unsigned)f2b(a3) << 16);
    *(uint2*)((ushort*)outp + (size_t)wid * 256 + f0) = o;
    // layer-1 mask: lane packs bits for h elements [gl*8, gl*8+8)
    unsigned gl = (unsigned)wid * 64u + (unsigned)lane;
    unsigned eb = gl * 8u;
    unsigned byte = 0;
#pragma unroll
    for (int j = 0; j < 8; ++j) {
      U2 r = threefry2x32(k10, k11, 0u, eb + (unsigned)j);
      byte |= (((r.a ^ r.b) >> 31) & 1u) << j;
    }
    mask1Gen[gl] = (unsigned char)byte;
  }
}

// ---------------------------------------------------------------------------
// bf16 MFMA GEMM: C[M,N] = A[M,K] @ BT[N,K]^T.  128x128 tile, BK=64, 4 waves,
// single-buffer 32KB staging, XOR-swizzled, swapped-operand mfma (lane holds
// 4 contiguous cols -> direct 8B C stores). 1-D grid, bijective XCD swizzle,
// N-strip fastest so same-A-tile blocks land adjacent on one XCD's L2.
// EPI: bias+relu+mask1-bit dropout.
// ---------------------------------------------------------------------------
template <bool EPI, int NSTRIP>
__global__ __launch_bounds__(256) void gemm_bf16(const ushort* __restrict__ A,
                                                 const ushort* __restrict__ BT,
                                                 ushort* __restrict__ C,
                                                 int M, int K, int N,
                                                 const float* __restrict__ bias,
                                                 const unsigned char* __restrict__ mask1) {
  __shared__ __align__(16) ushort lds[16384];  // A 16KB | B 16KB
  // bijective XCD swizzle (m204): each XCD gets a contiguous wg chunk
  const int nwg = gridDim.x;
  const int orig = blockIdx.x;
  const int q = nwg >> 3, r = nwg & 7;
  const int xcd = orig & 7, loc = orig >> 3;
  const int wg = (xcd < r) ? (xcd * (q + 1) + loc)
                           : (r * (q + 1) + (xcd - r) * q + loc);
  const int bm = (wg / NSTRIP) * 128;
  const int bn = (wg % NSTRIP) * 128;

  const int tid = threadIdx.x;
  const int lane = tid & 63;
  const int wv = tid >> 6;
  const int wr = wv >> 1, wc = wv & 1;

  f32x4 acc[4][4] = {};
  const int xorv = (lane & 7) << 4;

  const int nt = K >> 6;
  for (int t = 0; t < nt; ++t) {
    const int k0 = t << 6;
#pragma unroll
    for (int l = 0; l < 4; ++l) {
      int cid = l * 256 + tid;
      int row = cid >> 3;
      int kcol = ((cid & 7) ^ (row & 7)) * 8;
      gload16(A + (size_t)(bm + row) * K + k0 + kcol, (void*)(lds + cid * 8));
      gload16(BT + (size_t)(bn + row) * K + k0 + kcol, (void*)(lds + 8192 + cid * 8));
    }
    __syncthreads();
    const char* Ab = (const char*)lds;
    const char* Bb = (const char*)(lds + 8192);
#pragma unroll
    for (int ks = 0; ks < 2; ++ks) {
      bf16x8 af[4], bf[4];
      const int kb = (ks * 64 + (lane >> 4) * 16) ^ xorv;
#pragma unroll
      for (int i = 0; i < 4; ++i) {
        int arow = wr * 64 + i * 16 + (lane & 15);
        af[i] = *(const bf16x8*)(Ab + arow * 128 + kb);
        int brow = wc * 64 + i * 16 + (lane & 15);
        bf[i] = *(const bf16x8*)(Bb + brow * 128 + kb);
      }
      // swapped operands: D rows <- bf (n), D cols <- af (m)
#pragma unroll
      for (int m = 0; m < 4; ++m)
#pragma unroll
        for (int n = 0; n < 4; ++n)
          acc[m][n] = __builtin_amdgcn_mfma_f32_16x16x32_bf16(bf[n], af[m], acc[m][n], 0, 0, 0);
    }
    __syncthreads();
  }

  // epilogue: lane owns C[grow][gcol..gcol+3] per (m,n) -> direct 8B store
  const int growb = bm + wr * 64 + (lane & 15);
  const int gcolb = bn + wc * 64 + ((lane >> 4) << 2);
  float4 bias_v[4];
  if (EPI) {
#pragma unroll
    for (int n = 0; n < 4; ++n) bias_v[n] = *(const float4*)(bias + gcolb + n * 16);
  }
#pragma unroll
  for (int m = 0; m < 4; ++m) {
    int grow = growb + m * 16;
    unsigned long long mrow = 0;
    if (EPI)
      mrow = *(const unsigned long long*)(mask1 + (((size_t)grow * N + bn + wc * 64) >> 3));
#pragma unroll
    for (int n = 0; n < 4; ++n) {
      int gcol = gcolb + n * 16;
      float v[4];
#pragma unroll
      for (int r2 = 0; r2 < 4; ++r2) {
        float x = acc[m][n][r2];
        if (EPI) {
          x = fmaxf(x + ((const float*)&bias_v[n])[r2], 0.f);
          int bit = (gcol - (bn + wc * 64)) + r2;
          x = ((mrow >> bit) & 1ull) ? 0.f : x * 2.0f;
        }
        v[r2] = x;
      }
      uint2 o;
      o.x = (unsigned)f2b(v[0]) | ((unsigned)f2b(v[1]) << 16);
      o.y = (unsigned)f2b(v[2]) | ((unsigned)f2b(v[3]) << 16);
      *(uint2*)(C + (size_t)grow * N + gcol) = o;
    }
  }
}

// ---------------------------------------------------------------------------
extern "C" void kernel_launch(void* const* d_in, const int* in_sizes, int n_in,
                              void* d_out, int out_size, void* d_ws, size_t ws_size,
                              hipStream_t stream) {
  const float* x  = (const float*)d_in[0];
  const int*   ei = (const int*)d_in[1];
  const float* W1 = (const float*)d_in[2];
  const float* b1 = (const float*)d_in[3];
  const float* W2 = (const float*)d_in[4];
  const float* b2 = (const float*)d_in[5];
  float* out = (float*)d_out;
  (void)in_sizes; (void)n_in; (void)out_size; (void)ws_size;

  const int* row = ei;
  const int* col = ei + N_EDGES;

  // workspace layout (bytes)
  char* ws = (char*)d_ws;
  float*  dinv      = (float*) (ws);                           // 200 KB
  int*    cnt       = (int*)   (ws + (1u << 18));              // 200 KB
  int*    cursor    = (int*)   (ws + (2u << 18));              // 200 KB (adjacent)
  int*    indptr    = (int*)   (ws + (3u << 18));              // 200 KB + 4
  int*    chunkSums = (int*)   (ws + (1u << 20));              // tiny
  int2*   srcW      = (int2*)  (ws + 2u * (1u << 20));         // 6.4 MB
  ushort* W1T       = (ushort*)(ws + 9u * (1u << 20));         // 256 KB [512][256]
  ushort* W2T       = (ushort*)(ws + 9u * (1u << 20) + (1u << 19)); // 256 KB
  unsigned char* mask1 = (unsigned char*)(ws + 10u * (1u << 20)); // 3.21 MB
  unsigned char* mask2 = (unsigned char*)(ws + 14u * (1u << 20)); // 1.61 MB
  ushort* x16       = (ushort*)(ws + 18u * (1u << 20));        // 25.6 MB [50000][256]
  ushort* aggB      = (ushort*)(ws + 44u * (1u << 20));        // 25.6 MB [M_PAD][256]
  ushort* h         = (ushort*)(ws + 70u * (1u << 20));        // 51.2 MB [M_PAD][512]
  ushort* hw2       = (ushort*)(ws + 122u* (1u << 20));        // 25.6 MB [M_PAD][256]

  constexpr U2 K1 = threefry2x32(0u, 42u, 0u, 0u);
  constexpr U2 K2 = threefry2x32(0u, 42u, 0u, 1u);

  // ---- CSR build ----
  (void)hipMemsetAsync(cnt, 0, 2u * (1u << 18), stream);  // cnt + cursor
  deg_kernel<<<(N_EDGES + 255) / 256, 256, 0, stream>>>(col, cnt, N_EDGES);
  const int nChunks = (N_NODES + 1023) / 1024;
  scan_local<<<nChunks, 1024, 0, stream>>>(cnt, indptr, chunkSums, dinv, N_NODES);
  scan_add<<<(N_NODES + 255) / 256, 256, 0, stream>>>(indptr, chunkSums, N_NODES, nChunks, N_EDGES);
  build_csr<<<(N_EDGES + 255) / 256, 256, 0, stream>>>(row, col, indptr, cursor, dinv, srcW, N_EDGES);

  // ---- prep: cvt + mask2 + W transposes + aggB pad zero ----
  prep<<<(N_NODES * IN_C / 4 + 255) / 256, 256, 0, stream>>>(
      x, x16, N_NODES * IN_C / 4, mask2, K2.a, K2.b, N_NODES * 32,
      W1, W2, W1T, W2T, aggB + (size_t)N_NODES * IN_C);

  // ---- layer 1 ----
  gather8<false><<<(N_NODES + 3) / 4, 256, 0, stream>>>(
      x16, indptr, srcW, dinv, nullptr, aggB, mask1, nullptr, K1.a, K1.b, N_NODES);
  gemm_bf16<true, HID_C / 128><<<(M_PAD / 128) * (HID_C / 128), 256, 0, stream>>>(
      aggB, W1T, h, M_PAD, IN_C, HID_C, b1, mask1);

  // ---- layer 2 ----
  gemm_bf16<false, OUT_C / 128><<<(M_PAD / 128) * (OUT_C / 128), 256, 0, stream>>>(
      h, W2T, hw2, M_PAD, HID_C, OUT_C, nullptr, nullptr);
  gather8<true><<<(N_NODES + 3) / 4, 256, 0, stream>>>(
      hw2, indptr, srcW, dinv, b2, out, nullptr, mask2, 0u, 0u, N_NODES);
}

// Round 14
// 318.147 us; speedup vs baseline: 1.1289x; 1.0150x over previous
//
#include <hip/hip_runtime.h>
#include <stdint.h>

// ---------------------------------------------------------------------------
// GCN: agg1 = A_hat x (16-deep gather + mask1 bitmap)
//      h    = relu+drop(agg1 W1 + b1)   (MFMA GEMM, mask1 bit-test)
//      hw2  = h W2                      (MFMA GEMM, plain)
//      out  = relu+drop(A_hat hw2 + b2) (16-deep gather + mask2 bit-test)
// mask2 generated in the streaming prep kernel (VALU headroom).
// gather: __launch_bounds__(256,3) gives the allocator ~170 VGPR so the
// 16-deep load batches actually issue (plain bounds serialized to ~3-deep,
// VGPR_Count=16 — r13 tell). CSR entries carry {src_byte_off, dinv[src]}.
// ---------------------------------------------------------------------------

#define N_NODES 50000
#define N_EDGES 800000
#define M_PAD   50048   // 391 * 128
#define IN_C 256
#define HID_C 512
#define OUT_C 256

typedef __attribute__((ext_vector_type(8))) short bf16x8;
typedef __attribute__((ext_vector_type(4))) float f32x4;

struct U2 { unsigned a, b; };

__host__ __device__ constexpr unsigned rotl32(unsigned x, int d) {
  return (x << d) | (x >> (32 - d));
}

#define TF_ROUND(r) { x0 += x1; x1 = rotl32(x1, (r)); x1 ^= x0; }

__host__ __device__ constexpr U2 threefry2x32(unsigned k0, unsigned k1,
                                              unsigned x0, unsigned x1) {
  unsigned ks2 = k0 ^ k1 ^ 0x1BD11BDAu;
  x0 += k0; x1 += k1;
  TF_ROUND(13) TF_ROUND(15) TF_ROUND(26) TF_ROUND(6)  x0 += k1;  x1 += ks2 + 1u;
  TF_ROUND(17) TF_ROUND(29) TF_ROUND(16) TF_ROUND(24) x0 += ks2; x1 += k0 + 2u;
  TF_ROUND(13) TF_ROUND(15) TF_ROUND(26) TF_ROUND(6)  x0 += k0;  x1 += k1 + 3u;
  TF_ROUND(17) TF_ROUND(29) TF_ROUND(16) TF_ROUND(24) x0 += k1;  x1 += ks2 + 4u;
  TF_ROUND(13) TF_ROUND(15) TF_ROUND(26) TF_ROUND(6)  x0 += ks2; x1 += k0 + 5u;
  return U2{x0, x1};
}

__device__ __forceinline__ ushort f2b(float f) {  // RTNE
  unsigned u = __builtin_bit_cast(unsigned, f);
  unsigned r = (u + 0x7fffu + ((u >> 16) & 1u)) >> 16;
  return (ushort)r;
}
__device__ __forceinline__ float b2f(ushort h) {
  unsigned u = (unsigned)h << 16;
  return __builtin_bit_cast(float, u);
}

__device__ __forceinline__ void gload16(const void* g, void* l) {
  __builtin_amdgcn_global_load_lds(
      (const __attribute__((address_space(1))) void*)g,
      (__attribute__((address_space(3))) void*)l, 16, 0, 0);
}

// ---------------------------------------------------------------------------
// degree / scan(+dinv) / merged chunk-scan+add / CSR build
// CSR entry = {src*512 (byte offset), dinv[src]}
// ---------------------------------------------------------------------------
__global__ void deg_kernel(const int* __restrict__ col, int* __restrict__ cnt, int E) {
  int e = blockIdx.x * 256 + threadIdx.x;
  if (e < E) atomicAdd(&cnt[col[e]], 1);
}

__global__ __launch_bounds__(1024) void scan_local(const int* __restrict__ cnt,
                                                   int* __restrict__ indptr,
                                                   int* __restrict__ chunkSums,
                                                   float* __restrict__ dinv, int n) {
  __shared__ int s[1024];
  int gid = blockIdx.x * 1024 + threadIdx.x;
  int v = (gid < n) ? cnt[gid] : 0;
  if (gid < n) dinv[gid] = rsqrtf((float)v + 1.0f);
  s[threadIdx.x] = v;
  __syncthreads();
#pragma unroll
  for (int off = 1; off < 1024; off <<= 1) {
    int t = (threadIdx.x >= off) ? s[threadIdx.x - off] : 0;
    __syncthreads();
    s[threadIdx.x] += t;
    __syncthreads();
  }
  if (gid < n) indptr[gid] = s[threadIdx.x] - v;
  if (threadIdx.x == 1023) chunkSums[blockIdx.x] = s[1023];
}

// merged: first wave shfl-scans the <=64 chunk sums; all threads add offset.
__global__ void scan_add(int* __restrict__ indptr, const int* __restrict__ chunkSums,
                         int n, int nChunks, int total) {
  __shared__ int sc[64];
  int gid = blockIdx.x * 256 + threadIdx.x;
  if (threadIdx.x < 64) {
    int lane = threadIdx.x;
    int v = (lane < nChunks) ? chunkSums[lane] : 0;
    int incl = v;
#pragma unroll
    for (int off = 1; off < 64; off <<= 1) {
      int t = __shfl_up(incl, off);
      if (lane >= off) incl += t;
    }
    sc[lane] = incl - v;  // exclusive prefix
  }
  __syncthreads();
  if (gid < n) indptr[gid] += sc[gid >> 10];
  if (gid == 0) indptr[n] = total;
}

__global__ void build_csr(const int* __restrict__ row, const int* __restrict__ col,
                          const int* __restrict__ indptr, int* __restrict__ cursor,
                          const float* __restrict__ dinv,
                          int2* __restrict__ srcW, int E) {
  int e = blockIdx.x * 256 + threadIdx.x;
  if (e < E) {
    int r = row[e];
    int c = col[e];
    int p = indptr[c] + atomicAdd(&cursor[c], 1);
    srcW[p] = make_int2(r << 9, __builtin_bit_cast(int, dinv[r]));  // byte offset
  }
}

// ---------------------------------------------------------------------------
// prep: x->bf16 cvt, mask2 bitmap gen, W1T/W2T transpose-cvt, aggB pad zero.
// ---------------------------------------------------------------------------
__global__ void prep(const float* __restrict__ x, ushort* __restrict__ x16, int n4,
                     unsigned char* __restrict__ mask2,
                     unsigned k20, unsigned k21, int nMaskBytes,
                     const float* __restrict__ W1, const float* __restrict__ W2,
                     ushort* __restrict__ W1T, ushort* __restrict__ W2T,
                     ushort* __restrict__ padDst) {
  int i = blockIdx.x * 256 + threadIdx.x;
  if (i < n4) {
    float4 v = *(const float4*)(x + (size_t)i * 4);
    ushort4 o = make_ushort4(f2b(v.x), f2b(v.y), f2b(v.z), f2b(v.w));
    *(ushort4*)(x16 + (size_t)i * 4) = o;
  }
  if (i < nMaskBytes) {
    unsigned eb = (unsigned)i * 8u;
    unsigned byte = 0;
#pragma unroll
    for (int j = 0; j < 8; ++j) {
      U2 r = threefry2x32(k20, k21, 0u, eb + (unsigned)j);
      byte |= (((r.a ^ r.b) >> 31) & 1u) << j;
    }
    mask2[i] = (unsigned char)byte;
  }
  if (i < IN_C * HID_C) {        // W1T[n][k] = bf16(W1[k][n])
    int k = i & (IN_C - 1);
    int n = i >> 8;
    W1T[i] = f2b(W1[(size_t)k * HID_C + n]);
  } else if (i < IN_C * HID_C + HID_C * OUT_C) {
    int j = i - IN_C * HID_C;    // W2T[n][k] = bf16(W2[k][n])
    int k = j & (HID_C - 1);
    int n = j >> 9;
    W2T[j] = f2b(W2[(size_t)k * OUT_C + n]);
  }
  if (i < (M_PAD - N_NODES) * IN_C / 8) {  // zero pad rows of aggB
    uint4 z = {0u, 0u, 0u, 0u};
    *(uint4*)(padDst + (size_t)i * 8) = z;
  }
}

// ---------------------------------------------------------------------------
// gather over CSR pairs: one wave per node, 64 lanes x 8B, 16-deep batches
// (explicit arrays + (256,3) bounds so the allocator keeps them in flight).
// EPI=false: bf16 out + mask1 bitmap. EPI=true: bias+relu+mask2 drop, fp32.
// ---------------------------------------------------------------------------
#define ROW_ACC(vv, ww)                                                        \
  { a0 += b2f((vv).x) * (ww); a1 += b2f((vv).y) * (ww);                        \
    a2 += b2f((vv).z) * (ww); a3 += b2f((vv).w) * (ww); }

template <bool EPI>
__global__ __launch_bounds__(256, 3) void gather16(const ushort* __restrict__ X,
                                                   const int* __restrict__ indptr,
                                                   const int2* __restrict__ srcW,
                                                   const float* __restrict__ dinv,
                                                   const float* __restrict__ bias,
                                                   void* __restrict__ outp,
                                                   unsigned char* __restrict__ mask1Gen,
                                                   const unsigned char* __restrict__ maskUse,
                                                   unsigned k10, unsigned k11, int N) {
  int wid = (blockIdx.x * 256 + threadIdx.x) >> 6;
  int lane = threadIdx.x & 63;
  if (wid >= N) return;
  int beg = __builtin_amdgcn_readfirstlane(indptr[wid]);
  int end = __builtin_amdgcn_readfirstlane(indptr[wid + 1]);
  float dc = dinv[wid];
  const int f0 = lane * 4;
  const char* Xb = (const char*)X + (unsigned)(lane * 8);  // per-lane base
  ushort4 sv = *(const ushort4*)(Xb + ((size_t)wid << 9));
  float a0 = b2f(sv.x) * dc, a1 = b2f(sv.y) * dc,
        a2 = b2f(sv.z) * dc, a3 = b2f(sv.w) * dc;

  int e = beg;
  for (; e + 16 <= end; e += 16) {
    int2 q[16];
#pragma unroll
    for (int j = 0; j < 16; ++j) q[j] = srcW[e + j];
    ushort4 u[16];
#pragma unroll
    for (int j = 0; j < 16; ++j)
      u[j] = *(const ushort4*)(Xb + (unsigned)q[j].x);
#pragma unroll
    for (int j = 0; j < 16; ++j)
      ROW_ACC(u[j], __builtin_bit_cast(float, q[j].y));
  }
  for (; e + 4 <= end; e += 4) {
    int2 q[4];
#pragma unroll
    for (int j = 0; j < 4; ++j) q[j] = srcW[e + j];
    ushort4 u[4];
#pragma unroll
    for (int j = 0; j < 4; ++j)
      u[j] = *(const ushort4*)(Xb + (unsigned)q[j].x);
#pragma unroll
    for (int j = 0; j < 4; ++j)
      ROW_ACC(u[j], __builtin_bit_cast(float, q[j].y));
  }
  for (; e < end; ++e) {
    int2 q = srcW[e];
    ushort4 u = *(const ushort4*)(Xb + (unsigned)q.x);
    ROW_ACC(u, __builtin_bit_cast(float, q.y));
  }
  a0 *= dc; a1 *= dc; a2 *= dc; a3 *= dc;

  if (EPI) {
    float4 bv = *(const float4*)(bias + f0);
    unsigned mk = maskUse[(size_t)wid * 32 + (lane >> 1)];
    int sh = (lane & 1) * 4;
    float v0 = fmaxf(a0 + bv.x, 0.f);
    float v1 = fmaxf(a1 + bv.y, 0.f);
    float v2 = fmaxf(a2 + bv.z, 0.f);
    float v3 = fmaxf(a3 + bv.w, 0.f);
    v0 = ((mk >> (sh + 0)) & 1u) ? 0.f : v0 * 2.0f;
    v1 = ((mk >> (sh + 1)) & 1u) ? 0.f : v1 * 2.0f;
    v2 = ((mk >> (sh + 2)) & 1u) ? 0.f : v2 * 2.0f;
    v3 = ((mk >> (sh + 3)) & 1u) ? 0.f : v3 * 2.0f;
    *(float4*)((float*)outp + (size_t)wid * 256 + f0) = make_float4(v0, v1, v2, v3);
  } else {
    uint2 o;
    o.x = (unsigned)f2b(a0) | ((unsigned)f2b(a1) << 16);
    o.y = (unsigned)f2b(a2) | ((unsigned)f2b(a3) << 16);
    *(uint2*)((ushort*)outp + (size_t)wid * 256 + f0) = o;
    // layer-1 mask: lane packs bits for h elements [gl*8, gl*8+8)
    unsigned gl = (unsigned)wid * 64u + (unsigned)lane;
    unsigned eb = gl * 8u;
    unsigned byte = 0;
#pragma unroll
    for (int j = 0; j < 8; ++j) {
      U2 r = threefry2x32(k10, k11, 0u, eb + (unsigned)j);
      byte |= (((r.a ^ r.b) >> 31) & 1u) << j;
    }
    mask1Gen[gl] = (unsigned char)byte;
  }
}

// ---------------------------------------------------------------------------
// bf16 MFMA GEMM: C[M,N] = A[M,K] @ BT[N,K]^T.  128x128 tile, BK=64, 4 waves,
// single-buffer 32KB staging, XOR-swizzled, swapped-operand mfma (lane holds
// 4 contiguous cols -> direct 8B C stores). 1-D grid, bijective XCD swizzle,
// N-strip fastest so same-A-tile blocks land adjacent on one XCD's L2.
// EPI: bias+relu+mask1-bit dropout.
// ---------------------------------------------------------------------------
template <bool EPI, int NSTRIP>
__global__ __launch_bounds__(256) void gemm_bf16(const ushort* __restrict__ A,
                                                 const ushort* __restrict__ BT,
                                                 ushort* __restrict__ C,
                                                 int M, int K, int N,
                                                 const float* __restrict__ bias,
                                                 const unsigned char* __restrict__ mask1) {
  __shared__ __align__(16) ushort lds[16384];  // A 16KB | B 16KB
  // bijective XCD swizzle (m204): each XCD gets a contiguous wg chunk
  const int nwg = gridDim.x;
  const int orig = blockIdx.x;
  const int q = nwg >> 3, r = nwg & 7;
  const int xcd = orig & 7, loc = orig >> 3;
  const int wg = (xcd < r) ? (xcd * (q + 1) + loc)
                           : (r * (q + 1) + (xcd - r) * q + loc);
  const int bm = (wg / NSTRIP) * 128;
  const int bn = (wg % NSTRIP) * 128;

  const int tid = threadIdx.x;
  const int lane = tid & 63;
  const int wv = tid >> 6;
  const int wr = wv >> 1, wc = wv & 1;

  f32x4 acc[4][4] = {};
  const int xorv = (lane & 7) << 4;

  const int nt = K >> 6;
  for (int t = 0; t < nt; ++t) {
    const int k0 = t << 6;
#pragma unroll
    for (int l = 0; l < 4; ++l) {
      int cid = l * 256 + tid;
      int row = cid >> 3;
      int kcol = ((cid & 7) ^ (row & 7)) * 8;
      gload16(A + (size_t)(bm + row) * K + k0 + kcol, (void*)(lds + cid * 8));
      gload16(BT + (size_t)(bn + row) * K + k0 + kcol, (void*)(lds + 8192 + cid * 8));
    }
    __syncthreads();
    const char* Ab = (const char*)lds;
    const char* Bb = (const char*)(lds + 8192);
#pragma unroll
    for (int ks = 0; ks < 2; ++ks) {
      bf16x8 af[4], bf[4];
      const int kb = (ks * 64 + (lane >> 4) * 16) ^ xorv;
#pragma unroll
      for (int i = 0; i < 4; ++i) {
        int arow = wr * 64 + i * 16 + (lane & 15);
        af[i] = *(const bf16x8*)(Ab + arow * 128 + kb);
        int brow = wc * 64 + i * 16 + (lane & 15);
        bf[i] = *(const bf16x8*)(Bb + brow * 128 + kb);
      }
      // swapped operands: D rows <- bf (n), D cols <- af (m)
#pragma unroll
      for (int m = 0; m < 4; ++m)
#pragma unroll
        for (int n = 0; n < 4; ++n)
          acc[m][n] = __builtin_amdgcn_mfma_f32_16x16x32_bf16(bf[n], af[m], acc[m][n], 0, 0, 0);
    }
    __syncthreads();
  }

  // epilogue: lane owns C[grow][gcol..gcol+3] per (m,n) -> direct 8B store
  const int growb = bm + wr * 64 + (lane & 15);
  const int gcolb = bn + wc * 64 + ((lane >> 4) << 2);
  float4 bias_v[4];
  if (EPI) {
#pragma unroll
    for (int n = 0; n < 4; ++n) bias_v[n] = *(const float4*)(bias + gcolb + n * 16);
  }
#pragma unroll
  for (int m = 0; m < 4; ++m) {
    int grow = growb + m * 16;
    unsigned long long mrow = 0;
    if (EPI)
      mrow = *(const unsigned long long*)(mask1 + (((size_t)grow * N + bn + wc * 64) >> 3));
#pragma unroll
    for (int n = 0; n < 4; ++n) {
      int gcol = gcolb + n * 16;
      float v[4];
#pragma unroll
      for (int r2 = 0; r2 < 4; ++r2) {
        float x = acc[m][n][r2];
        if (EPI) {
          x = fmaxf(x + ((const float*)&bias_v[n])[r2], 0.f);
          int bit = (gcol - (bn + wc * 64)) + r2;
          x = ((mrow >> bit) & 1ull) ? 0.f : x * 2.0f;
        }
        v[r2] = x;
      }
      uint2 o;
      o.x = (unsigned)f2b(v[0]) | ((unsigned)f2b(v[1]) << 16);
      o.y = (unsigned)f2b(v[2]) | ((unsigned)f2b(v[3]) << 16);
      *(uint2*)(C + (size_t)grow * N + gcol) = o;
    }
  }
}

// ---------------------------------------------------------------------------
extern "C" void kernel_launch(void* const* d_in, const int* in_sizes, int n_in,
                              void* d_out, int out_size, void* d_ws, size_t ws_size,
                              hipStream_t stream) {
  const float* x  = (const float*)d_in[0];
  const int*   ei = (const int*)d_in[1];
  const float* W1 = (const float*)d_in[2];
  const float* b1 = (const float*)d_in[3];
  const float* W2 = (const float*)d_in[4];
  const float* b2 = (const float*)d_in[5];
  float* out = (float*)d_out;
  (void)in_sizes; (void)n_in; (void)out_size; (void)ws_size;

  const int* row = ei;
  const int* col = ei + N_EDGES;

  // workspace layout (bytes)
  char* ws = (char*)d_ws;
  float*  dinv      = (float*) (ws);                           // 200 KB
  int*    cnt       = (int*)   (ws + (1u << 18));              // 200 KB
  int*    cursor    = (int*)   (ws + (2u << 18));              // 200 KB (adjacent)
  int*    indptr    = (int*)   (ws + (3u << 18));              // 200 KB + 4
  int*    chunkSums = (int*)   (ws + (1u << 20));              // tiny
  int2*   srcW      = (int2*)  (ws + 2u * (1u << 20));         // 6.4 MB
  ushort* W1T       = (ushort*)(ws + 9u * (1u << 20));         // 256 KB [512][256]
  ushort* W2T       = (ushort*)(ws + 9u * (1u << 20) + (1u << 19)); // 256 KB
  unsigned char* mask1 = (unsigned char*)(ws + 10u * (1u << 20)); // 3.21 MB
  unsigned char* mask2 = (unsigned char*)(ws + 14u * (1u << 20)); // 1.61 MB
  ushort* x16       = (ushort*)(ws + 18u * (1u << 20));        // 25.6 MB [50000][256]
  ushort* aggB      = (ushort*)(ws + 44u * (1u << 20));        // 25.6 MB [M_PAD][256]
  ushort* h         = (ushort*)(ws + 70u * (1u << 20));        // 51.2 MB [M_PAD][512]
  ushort* hw2       = (ushort*)(ws + 122u* (1u << 20));        // 25.6 MB [M_PAD][256]

  constexpr U2 K1 = threefry2x32(0u, 42u, 0u, 0u);
  constexpr U2 K2 = threefry2x32(0u, 42u, 0u, 1u);

  // ---- CSR build ----
  (void)hipMemsetAsync(cnt, 0, 2u * (1u << 18), stream);  // cnt + cursor
  deg_kernel<<<(N_EDGES + 255) / 256, 256, 0, stream>>>(col, cnt, N_EDGES);
  const int nChunks = (N_NODES + 1023) / 1024;
  scan_local<<<nChunks, 1024, 0, stream>>>(cnt, indptr, chunkSums, dinv, N_NODES);
  scan_add<<<(N_NODES + 255) / 256, 256, 0, stream>>>(indptr, chunkSums, N_NODES, nChunks, N_EDGES);
  build_csr<<<(N_EDGES + 255) / 256, 256, 0, stream>>>(row, col, indptr, cursor, dinv, srcW, N_EDGES);

  // ---- prep: cvt + mask2 + W transposes + aggB pad zero ----
  prep<<<(N_NODES * IN_C / 4 + 255) / 256, 256, 0, stream>>>(
      x, x16, N_NODES * IN_C / 4, mask2, K2.a, K2.b, N_NODES * 32,
      W1, W2, W1T, W2T, aggB + (size_t)N_NODES * IN_C);

  // ---- layer 1 ----
  gather16<false><<<(N_NODES + 3) / 4, 256, 0, stream>>>(
      x16, indptr, srcW, dinv, nullptr, aggB, mask1, nullptr, K1.a, K1.b, N_NODES);
  gemm_bf16<true, HID_C / 128><<<(M_PAD / 128) * (HID_C / 128), 256, 0, stream>>>(
      aggB, W1T, h, M_PAD, IN_C, HID_C, b1, mask1);

  // ---- layer 2 ----
  gemm_bf16<false, OUT_C / 128><<<(M_PAD / 128) * (OUT_C / 128), 256, 0, stream>>>(
      h, W2T, hw2, M_PAD, HID_C, OUT_C, nullptr, nullptr);
  gather16<true><<<(N_NODES + 3) / 4, 256, 0, stream>>>(
      hw2, indptr, srcW, dinv, b2, out, nullptr, mask2, 0u, 0u, N_NODES);
}